// Round 1
// 128.605 us; speedup vs baseline: 1.0042x; 1.0042x over previous
//
#include <hip/hip_runtime.h>
#include <math.h>

typedef _Float16 f16;
typedef f16   f16x4    __attribute__((ext_vector_type(4)));
typedef f16   f16x8    __attribute__((ext_vector_type(8)));
typedef float floatx4  __attribute__((ext_vector_type(4)));
typedef float floatx16 __attribute__((ext_vector_type(16)));

#define LOG2E 1.44269504088896340736f

// Problem constants
#define B_SZ  2048
#define DIN   64
#define DOUT  64
#define NH    32

#define NIG   4                 // i-groups (occupancy: 8192 blocks)
#define IGW   (DIN / NIG)       // 16 i per block

// Images (built by prep_kernel), now K=8-packed for mfma_32x32x8 (no zero half):
//  w1img f16 [i][o][lane(64)][j(4)]: A-frag, m=h=lane&31, k=(lane>>5)*4+j.
//        lane<32 -> k=0..3 -> W1[...,{x,s1,s2,s4}]; lane>=32 -> k=4..7 ->
//        {W1[4],W1[5],W1[6],B1} (bias via constant-1 feature). Scaled by -log2e.
//  fimg  f16 [i][btp(64)][lane(64)][j(4)]: B-frag, n=b=lane&31, k as above;
//        lane<32 -> {x,s1,s2,s4}; lane>=32 -> {c1,c2,c4,1}.
//  w2q   f32 [i][o][h(32)] = W2[i,o,h] * (-1/log2e)   (h-linear)
//  b2sum f32 [64]: column sums of B2.
#define W1IMG_ELEMS ((size_t)DIN * DOUT * 64 * 4)   // 1,048,576 f16 = 2 MB
#define FIMG_ELEMS  ((size_t)DIN * 64 * 64 * 4)     // 1,048,576 f16 = 2 MB
#define W2Q_ELEMS   ((size_t)DIN * DOUT * NH)       // 131,072 f32 = 512 KB

// ---------------------------------------------------------------------------
// prep: bid [0,512) -> w1img, [512,1024) -> fimg, [1024,1152) -> w2q (float4
// scaled copy), [1152,1280) -> zero out[], 1280 -> b2sum.
// Each image thread packs TWO adjacent lanes (16B coalesced store).
// ---------------------------------------------------------------------------
__global__ __launch_bounds__(256) void prep_kernel(
        const float* __restrict__ W1, const float* __restrict__ B1,
        const float* __restrict__ W2, const float* __restrict__ B2,
        const float* __restrict__ x,
        f16* __restrict__ w1img, f16* __restrict__ fimg,
        float* __restrict__ w2q, float* __restrict__ b2sum,
        float* __restrict__ out) {
    const int bid = blockIdx.x, tid = threadIdx.x;
    if (bid < 512) {
        int u = bid * 256 + tid;             // [i][o][lane2] lane2 = lane pair
        int lane2 = u & 31, o = (u >> 5) & 63, i = u >> 11;
        int l0 = lane2 * 2;
        f16x8 v;
        if (lane2 < 16) {                    // rows l0,l0+1; k=0..3 -> w[0..3]
#pragma unroll
            for (int t = 0; t < 2; ++t) {
                const float* w = W1 + (size_t)((i * 64 + o) * 32 + l0 + t) * 7;
#pragma unroll
                for (int j = 0; j < 4; ++j) v[t * 4 + j] = (f16)(w[j] * (-LOG2E));
            }
        } else {                             // rows l0-32,l0-31; k=4..7 -> w[4..6],B1
#pragma unroll
            for (int t = 0; t < 2; ++t) {
                int m = l0 - 32 + t;
                const float* w = W1 + (size_t)((i * 64 + o) * 32 + m) * 7;
                v[t * 4 + 0] = (f16)(w[4] * (-LOG2E));
                v[t * 4 + 1] = (f16)(w[5] * (-LOG2E));
                v[t * 4 + 2] = (f16)(w[6] * (-LOG2E));
                v[t * 4 + 3] = (f16)(B1[(i * 64 + o) * 32 + m] * (-LOG2E));
            }
        }
        *(f16x8*)(w1img + (size_t)u * 8) = v;
    } else if (bid < 1024) {
        int u = (bid - 512) * 256 + tid;     // [i][btp][lane2]
        int lane2 = u & 31, btp = (u >> 5) & 63, i = u >> 11;
        int l0 = lane2 * 2;
        f16x8 v;
#pragma unroll
        for (int t = 0; t < 2; ++t) {
            int b = btp * 32 + ((l0 + t) & 31);
            float xv = x[b * 64 + i];
            float s1, c1;
            __sincosf(xv, &s1, &c1);
            float s2 = 2.0f * s1 * c1, c2 = 1.0f - 2.0f * s1 * s1;
            float s4 = 2.0f * s2 * c2, c4 = 1.0f - 2.0f * s2 * s2;
            if (lane2 < 16) { v[t*4+0] = (f16)xv; v[t*4+1] = (f16)s1;
                              v[t*4+2] = (f16)s2; v[t*4+3] = (f16)s4; }
            else            { v[t*4+0] = (f16)c1; v[t*4+1] = (f16)c2;
                              v[t*4+2] = (f16)c4; v[t*4+3] = (f16)1.0f; }
        }
        *(f16x8*)(fimg + (size_t)u * 8) = v;
    } else if (bid < 1152) {
        int t = (bid - 1024) * 256 + tid;    // < 32768 float4s
        floatx4 v = *(const floatx4*)(W2 + (size_t)t * 4);
        v *= (-1.0f / LOG2E);
        *(floatx4*)(w2q + (size_t)t * 4) = v;
    } else if (bid < 1280) {
        int t = (bid - 1152) * 256 + tid;    // zero out[] (atomics accumulate)
        floatx4 z = {};
        *(floatx4*)(out + (size_t)t * 4) = z;
    } else if (tid < 64) {
        float s = 0.0f;
        for (int i = 0; i < 64; ++i) s += B2[i * 64 + tid];
        b2sum[tid] = s;
    }
}

// ---------------------------------------------------------------------------
// main: grid = 4 ig x 32 og x 64 btp = 8192 blocks, block = 128 (2 waves);
// wave w -> o = og*2+w, i in [ig*16, ig*16+16). Per i: ONE mfma_32x32x8
// (K=8 exact, no wasted zero half) -> C[h(32) x b(32)]. w2 slice staged in
// LDS once per block (broadcast ds_read_b128, conflict-free). silu
// in-register; 4 phi accumulators break the fma chain. Results atomically
// added to out (hw global_atomic_add_f32), carrying 1/NIG of b2sum each.
// ---------------------------------------------------------------------------
__global__ __launch_bounds__(128, 4) void main_kernel(
        const f16* __restrict__ w1img, const f16* __restrict__ fimg,
        const float* __restrict__ w2q, const float* __restrict__ b2sum,
        float* __restrict__ out) {
    const int tid  = threadIdx.x;
    const int lane = tid & 63;
    const int wv   = tid >> 6;
    const int btp  = blockIdx.x & 63;
    const int og   = (blockIdx.x >> 6) & 31;
    const int ig   = blockIdx.x >> 11;
    const int o    = __builtin_amdgcn_readfirstlane(og * 2 + wv);
    const int p    = lane >> 5;
    const size_t ibase = (size_t)ig * IGW;

    // stage w2 slice: [wave][ii][h] = 2*16*32 floats = 4 KB
    __shared__ float ws2[2][IGW][32];
    {
        int idx = tid * 8;                         // 8 floats per thread
        int wv_ = idx >> 9, ii_ = (idx >> 5) & 15, h_ = idx & 31;
        const float* src = w2q + (ibase + ii_) * 2048
                         + (size_t)(og * 2 + wv_) * 32 + h_;
        *(floatx4*)&ws2[wv_][ii_][h_]     = *(const floatx4*)src;
        *(floatx4*)&ws2[wv_][ii_][h_ + 4] = *(const floatx4*)(src + 4);
    }
    __syncthreads();

    const f16* ap = w1img + ibase * 16384 + ((size_t)o   * 64 + lane) * 4;
    const f16* bp = fimg  + ibase * 16384 + ((size_t)btp * 64 + lane) * 4;

    // prefetch ii = 0
    f16x4 a = *(const f16x4*)ap;
    f16x4 b = *(const f16x4*)bp;

    float phi0 = 0.0f, phi1 = 0.0f, phi2 = 0.0f, phi3 = 0.0f;
    const floatx16 zeroC = {};

#pragma unroll 1
    for (int ii = 0; ii < IGW; ++ii) {
        const f16x4 ca = a, cb = b;

        // prefetch ii+1 (last iter overruns into adjacent ws regions — values
        // loaded but never consumed; regions are contiguous and padded)
        const size_t i1 = (size_t)(ii + 1);
        a = *(const f16x4*)(ap + i1 * 16384);
        b = *(const f16x4*)(bp + i1 * 16384);

        const float* wrow = &ws2[wv][ii][p * 4];
        const floatx4 cw0 = *(const floatx4*)(wrow);
        const floatx4 cw1 = *(const floatx4*)(wrow + 8);
        const floatx4 cw2 = *(const floatx4*)(wrow + 16);
        const floatx4 cw3 = *(const floatx4*)(wrow + 24);

        floatx16 C = __builtin_amdgcn_mfma_f32_32x32x8f16(ca, cb, zeroC, 0, 0, 0);

#pragma unroll
        for (int r = 0; r < 4; ++r) {
            float av, e2, sg;
            av = C[0 + r];  e2 = __builtin_amdgcn_exp2f(av);
            sg = __builtin_amdgcn_rcpf(1.0f + e2);
            phi0 = __builtin_fmaf(av * cw0[r], sg, phi0);
            av = C[4 + r];  e2 = __builtin_amdgcn_exp2f(av);
            sg = __builtin_amdgcn_rcpf(1.0f + e2);
            phi1 = __builtin_fmaf(av * cw1[r], sg, phi1);
            av = C[8 + r];  e2 = __builtin_amdgcn_exp2f(av);
            sg = __builtin_amdgcn_rcpf(1.0f + e2);
            phi2 = __builtin_fmaf(av * cw2[r], sg, phi2);
            av = C[12 + r]; e2 = __builtin_amdgcn_exp2f(av);
            sg = __builtin_amdgcn_rcpf(1.0f + e2);
            phi3 = __builtin_fmaf(av * cw3[r], sg, phi3);
        }
    }

    float phi = (phi0 + phi1) + (phi2 + phi3);
    // combine the two row-halves (lane and lane^32 share the same column)
    phi += __shfl_xor(phi, 32, 64);

    if (lane < 32) {
        float v = phi + 0.25f * b2sum[o];   // 1/NIG of bias per contribution
        unsafeAtomicAdd(out + (size_t)(btp * 32 + lane) * 64 + o, v);
    }
}

extern "C" void kernel_launch(void* const* d_in, const int* in_sizes, int n_in,
                              void* d_out, int out_size, void* d_ws, size_t ws_size,
                              hipStream_t stream) {
    const float* x  = (const float*)d_in[0];
    const float* W1 = (const float*)d_in[1];
    const float* W2 = (const float*)d_in[2];
    const float* B1 = (const float*)d_in[3];
    const float* B2 = (const float*)d_in[4];
    float* out = (float*)d_out;

    // ws: w1img (2MB) | fimg (2MB) | w2q (512KB) | b2sum | (overrun pad lives
    // in the contiguity of these regions; prefetch spills land in-bounds)
    f16*   w1img = (f16*)d_ws;
    f16*   fimg  = w1img + W1IMG_ELEMS;
    float* w2q   = (float*)(fimg + FIMG_ELEMS);
    float* b2sum = w2q + W2Q_ELEMS;

    prep_kernel<<<1281, 256, 0, stream>>>(W1, B1, W2, B2, x, w1img, fimg, w2q, b2sum, out);
    main_kernel<<<NIG * 32 * 64, 128, 0, stream>>>(w1img, fimg, w2q, b2sum, out);
}

// Round 2
// 113.297 us; speedup vs baseline: 1.1399x; 1.1351x over previous
//
#include <hip/hip_runtime.h>
#include <math.h>

typedef _Float16 f16;
typedef f16   f16x4    __attribute__((ext_vector_type(4)));
typedef f16   f16x8    __attribute__((ext_vector_type(8)));
typedef float floatx4  __attribute__((ext_vector_type(4)));
typedef float floatx16 __attribute__((ext_vector_type(16)));

#define LOG2E 1.44269504088896340736f

// Problem constants
#define B_SZ  2048
#define DIN   64
#define DOUT  64
#define NH    32

#define NIG   4                 // i-groups (occupancy: 8192 blocks)
#define IGW   (DIN / NIG)       // 16 i per block

// Images (built by prep_kernel), K=8-packed for mfma_32x32x8 (no zero half):
//  w1img f16 [i][o][lane(64)][j(4)]: A-frag, m=h=lane&31, k=(lane>>5)*4+j.
//        lane<32 -> k=0..3 -> W1[...,{x,s1,s2,s4}]; lane>=32 -> k=4..7 ->
//        {W1[4],W1[5],W1[6],B1} (bias via constant-1 feature). Scaled by -log2e.
//  fimg  f16 [i][btp(64)][lane(64)][j(4)]: B-frag, n=b=lane&31, k as above;
//        lane<32 -> {x,s1,s2,s4}; lane>=32 -> {c1,c2,c4,1}.
//  w2q   f32 [i][o][h(32)] = W2[i,o,h] * (-1/log2e)   (h-linear)
//  b2sum f32 [64]: column sums of B2.
#define W1IMG_ELEMS ((size_t)DIN * DOUT * 64 * 4)   // 1,048,576 f16 = 2 MB
#define FIMG_ELEMS  ((size_t)DIN * 64 * 64 * 4)     // 1,048,576 f16 = 2 MB
#define W2Q_ELEMS   ((size_t)DIN * DOUT * NH)       // 131,072 f32 = 512 KB

// ---------------------------------------------------------------------------
// prep: bid [0,512) -> w1img, [512,1024) -> fimg, [1024,1152) -> w2q (float4
// scaled copy), [1152,1280) -> zero out[], 1280 -> b2sum.
// Each image thread packs TWO adjacent lanes (16B coalesced store).
// ---------------------------------------------------------------------------
__global__ __launch_bounds__(256) void prep_kernel(
        const float* __restrict__ W1, const float* __restrict__ B1,
        const float* __restrict__ W2, const float* __restrict__ B2,
        const float* __restrict__ x,
        f16* __restrict__ w1img, f16* __restrict__ fimg,
        float* __restrict__ w2q, float* __restrict__ b2sum,
        float* __restrict__ out) {
    const int bid = blockIdx.x, tid = threadIdx.x;
    if (bid < 512) {
        int u = bid * 256 + tid;             // [i][o][lane2] lane2 = lane pair
        int lane2 = u & 31, o = (u >> 5) & 63, i = u >> 11;
        int l0 = lane2 * 2;
        f16x8 v;
        if (lane2 < 16) {                    // rows l0,l0+1; k=0..3 -> w[0..3]
#pragma unroll
            for (int t = 0; t < 2; ++t) {
                const float* w = W1 + (size_t)((i * 64 + o) * 32 + l0 + t) * 7;
#pragma unroll
                for (int j = 0; j < 4; ++j) v[t * 4 + j] = (f16)(w[j] * (-LOG2E));
            }
        } else {                             // rows l0-32,l0-31; k=4..7 -> w[4..6],B1
#pragma unroll
            for (int t = 0; t < 2; ++t) {
                int m = l0 - 32 + t;
                const float* w = W1 + (size_t)((i * 64 + o) * 32 + m) * 7;
                v[t * 4 + 0] = (f16)(w[4] * (-LOG2E));
                v[t * 4 + 1] = (f16)(w[5] * (-LOG2E));
                v[t * 4 + 2] = (f16)(w[6] * (-LOG2E));
                v[t * 4 + 3] = (f16)(B1[(i * 64 + o) * 32 + m] * (-LOG2E));
            }
        }
        *(f16x8*)(w1img + (size_t)u * 8) = v;
    } else if (bid < 1024) {
        int u = (bid - 512) * 256 + tid;     // [i][btp][lane2]
        int lane2 = u & 31, btp = (u >> 5) & 63, i = u >> 11;
        int l0 = lane2 * 2;
        f16x8 v;
#pragma unroll
        for (int t = 0; t < 2; ++t) {
            int b = btp * 32 + ((l0 + t) & 31);
            float xv = x[b * 64 + i];
            float s1, c1;
            __sincosf(xv, &s1, &c1);
            float s2 = 2.0f * s1 * c1, c2 = 1.0f - 2.0f * s1 * s1;
            float s4 = 2.0f * s2 * c2, c4 = 1.0f - 2.0f * s2 * s2;
            if (lane2 < 16) { v[t*4+0] = (f16)xv; v[t*4+1] = (f16)s1;
                              v[t*4+2] = (f16)s2; v[t*4+3] = (f16)s4; }
            else            { v[t*4+0] = (f16)c1; v[t*4+1] = (f16)c2;
                              v[t*4+2] = (f16)c4; v[t*4+3] = (f16)1.0f; }
        }
        *(f16x8*)(fimg + (size_t)u * 8) = v;
    } else if (bid < 1152) {
        int t = (bid - 1024) * 256 + tid;    // < 32768 float4s
        floatx4 v = *(const floatx4*)(W2 + (size_t)t * 4);
        v *= (-1.0f / LOG2E);
        *(floatx4*)(w2q + (size_t)t * 4) = v;
    } else if (bid < 1280) {
        int t = (bid - 1152) * 256 + tid;    // zero out[] (atomics accumulate)
        floatx4 z = {};
        *(floatx4*)(out + (size_t)t * 4) = z;
    } else if (tid < 64) {
        float s = 0.0f;
        for (int i = 0; i < 64; ++i) s += B2[i * 64 + tid];
        b2sum[tid] = s;
    }
}

// ---------------------------------------------------------------------------
// main: grid = 4 ig x 32 og x 64 btp = 8192 blocks, block = 128 (2 waves);
// wave w -> o = og*2+w, i in [ig*16, ig*16+16). Per i: ONE mfma_32x32x8
// (K=8 exact) -> C[h(32) x b(32)]. w2 slice staged in LDS (broadcast
// ds_read_b128). silu in-register with 4-WAY BATCHED RECIPROCALS:
//   sum_i u_i/(1+e_i) = [pairwise-combined numerator] / prod(1+e_i)
// -> 5 trans + 15 VALU per 4 activations instead of 8 trans + 12 VALU.
// (prod of 4 d_i <= e^(sum|a|); overflows f32 only if sum|a| > 88 in a
// group — preacts here are O(5), ~10x headroom.)
// Results atomically added to out, carrying 1/NIG of b2sum each.
// ---------------------------------------------------------------------------
__global__ __launch_bounds__(128, 4) void main_kernel(
        const f16* __restrict__ w1img, const f16* __restrict__ fimg,
        const float* __restrict__ w2q, const float* __restrict__ b2sum,
        float* __restrict__ out) {
    const int tid  = threadIdx.x;
    const int lane = tid & 63;
    const int wv   = tid >> 6;
    const int btp  = blockIdx.x & 63;
    const int og   = (blockIdx.x >> 6) & 31;
    const int ig   = blockIdx.x >> 11;
    const int o    = __builtin_amdgcn_readfirstlane(og * 2 + wv);
    const int p    = lane >> 5;
    const size_t ibase = (size_t)ig * IGW;

    // stage w2 slice: [wave][ii][h] = 2*16*32 floats = 4 KB
    __shared__ float ws2[2][IGW][32];
    {
        int idx = tid * 8;                         // 8 floats per thread
        int wv_ = idx >> 9, ii_ = (idx >> 5) & 15, h_ = idx & 31;
        const float* src = w2q + (ibase + ii_) * 2048
                         + (size_t)(og * 2 + wv_) * 32 + h_;
        *(floatx4*)&ws2[wv_][ii_][h_]     = *(const floatx4*)src;
        *(floatx4*)&ws2[wv_][ii_][h_ + 4] = *(const floatx4*)(src + 4);
    }
    __syncthreads();

    const f16* ap = w1img + ibase * 16384 + ((size_t)o   * 64 + lane) * 4;
    const f16* bp = fimg  + ibase * 16384 + ((size_t)btp * 64 + lane) * 4;

    // prefetch ii = 0
    f16x4 a = *(const f16x4*)ap;
    f16x4 b = *(const f16x4*)bp;

    float phi0 = 0.0f, phi1 = 0.0f, phi2 = 0.0f, phi3 = 0.0f;
    const floatx16 zeroC = {};

#pragma unroll 1
    for (int ii = 0; ii < IGW; ++ii) {
        const f16x4 ca = a, cb = b;

        // prefetch ii+1 (last iter overruns into adjacent ws regions — values
        // loaded but never consumed; regions are contiguous and padded)
        const size_t i1 = (size_t)(ii + 1);
        a = *(const f16x4*)(ap + i1 * 16384);
        b = *(const f16x4*)(bp + i1 * 16384);

        const float* wrow = &ws2[wv][ii][p * 4];
        const floatx4 cw0 = *(const floatx4*)(wrow);
        const floatx4 cw1 = *(const floatx4*)(wrow + 8);
        const floatx4 cw2 = *(const floatx4*)(wrow + 16);
        const floatx4 cw3 = *(const floatx4*)(wrow + 24);

        floatx16 C = __builtin_amdgcn_mfma_f32_32x32x8f16(ca, cb, zeroC, 0, 0, 0);

#pragma unroll
        for (int r = 0; r < 4; ++r) {
            // group of 4 activations sharing ONE reciprocal:
            //   sum u_i/d_i,  d_i = 1 + 2^(a_i''),  u_i = a_i''*w2_i''
            float a0 = C[0 + r], a1 = C[4 + r], a2 = C[8 + r], a3 = C[12 + r];
            float e0 = __builtin_amdgcn_exp2f(a0);
            float e1 = __builtin_amdgcn_exp2f(a1);
            float e2 = __builtin_amdgcn_exp2f(a2);
            float e3 = __builtin_amdgcn_exp2f(a3);
            float d0 = 1.0f + e0, d1 = 1.0f + e1;
            float d2 = 1.0f + e2, d3 = 1.0f + e3;
            float u0 = a0 * cw0[r], u1 = a1 * cw1[r];
            float u2 = a2 * cw2[r], u3 = a3 * cw3[r];
            float n01 = __builtin_fmaf(u0, d1, u1 * d0);
            float n23 = __builtin_fmaf(u2, d3, u3 * d2);
            float d01 = d0 * d1, d23 = d2 * d3;
            float n   = __builtin_fmaf(n01, d23, n23 * d01);
            float rr  = __builtin_amdgcn_rcpf(d01 * d23);
            if (r == 0)      phi0 = __builtin_fmaf(n, rr, phi0);
            else if (r == 1) phi1 = __builtin_fmaf(n, rr, phi1);
            else if (r == 2) phi2 = __builtin_fmaf(n, rr, phi2);
            else             phi3 = __builtin_fmaf(n, rr, phi3);
        }
    }

    float phi = (phi0 + phi1) + (phi2 + phi3);
    // combine the two row-halves (lane and lane^32 share the same column)
    phi += __shfl_xor(phi, 32, 64);

    if (lane < 32) {
        float v = phi + 0.25f * b2sum[o];   // 1/NIG of bias per contribution
        unsafeAtomicAdd(out + (size_t)(btp * 32 + lane) * 64 + o, v);
    }
}

extern "C" void kernel_launch(void* const* d_in, const int* in_sizes, int n_in,
                              void* d_out, int out_size, void* d_ws, size_t ws_size,
                              hipStream_t stream) {
    const float* x  = (const float*)d_in[0];
    const float* W1 = (const float*)d_in[1];
    const float* W2 = (const float*)d_in[2];
    const float* B1 = (const float*)d_in[3];
    const float* B2 = (const float*)d_in[4];
    float* out = (float*)d_out;

    // ws: w1img (2MB) | fimg (2MB) | w2q (512KB) | b2sum | (overrun pad lives
    // in the contiguity of these regions; prefetch spills land in-bounds)
    f16*   w1img = (f16*)d_ws;
    f16*   fimg  = w1img + W1IMG_ELEMS;
    float* w2q   = (float*)(fimg + FIMG_ELEMS);
    float* b2sum = w2q + W2Q_ELEMS;

    prep_kernel<<<1281, 256, 0, stream>>>(W1, B1, W2, B2, x, w1img, fimg, w2q, b2sum, out);
    main_kernel<<<NIG * 32 * 64, 128, 0, stream>>>(w1img, fimg, w2q, b2sum, out);
}

// Round 4
// 112.847 us; speedup vs baseline: 1.1444x; 1.0040x over previous
//
#include <hip/hip_runtime.h>
#include <math.h>

typedef _Float16 f16;
typedef f16   f16x4    __attribute__((ext_vector_type(4)));
typedef f16   f16x8    __attribute__((ext_vector_type(8)));
typedef float floatx4  __attribute__((ext_vector_type(4)));
typedef float floatx16 __attribute__((ext_vector_type(16)));

#define LOG2E 1.44269504088896340736f

// Problem constants
#define B_SZ  2048
#define DIN   64
#define DOUT  64
#define NH    32

#define NIG   4                 // i-groups (occupancy: 8192 blocks)
#define IGW   (DIN / NIG)       // 16 i per block

// Images (built by prep_kernel), K=8-packed for mfma_32x32x8 (no zero half):
//  w1img f16 [i][o][lane(64)][j(4)]: A-frag, m=h=lane&31, k=(lane>>5)*4+j.
//        lane<32 -> k=0..3 -> W1[...,{x,s1,s2,s4}]; lane>=32 -> k=4..7 ->
//        {W1[4],W1[5],W1[6],B1} (bias via constant-1 feature). Scaled by -log2e.
//  fimg  f16 [i][btp(64)][lane(64)][j(4)]: B-frag, n=b=lane&31, k as above;
//        lane<32 -> {x,s1,s2,s4}; lane>=32 -> {c1,c2,c4,1}.
//  w2q   f32 [i][o][h(32)] = W2[i,o,h] * (-1/log2e)   (h-linear)
//  b2sum f32 [64]: column sums of B2.
#define W1IMG_ELEMS ((size_t)DIN * DOUT * 64 * 4)   // 1,048,576 f16 = 2 MB
#define FIMG_ELEMS  ((size_t)DIN * 64 * 64 * 4)     // 1,048,576 f16 = 2 MB
#define W2Q_ELEMS   ((size_t)DIN * DOUT * NH)       // 131,072 f32 = 512 KB

// ---------------------------------------------------------------------------
// prep: bid [0,512) -> w1img, [512,1024) -> fimg, [1024,1152) -> w2q (float4
// scaled copy), [1152,1280) -> zero out[], 1280 -> b2sum.
// Each image thread packs TWO adjacent lanes (16B coalesced store).
// ---------------------------------------------------------------------------
__global__ __launch_bounds__(256) void prep_kernel(
        const float* __restrict__ W1, const float* __restrict__ B1,
        const float* __restrict__ W2, const float* __restrict__ B2,
        const float* __restrict__ x,
        f16* __restrict__ w1img, f16* __restrict__ fimg,
        float* __restrict__ w2q, float* __restrict__ b2sum,
        float* __restrict__ out) {
    const int bid = blockIdx.x, tid = threadIdx.x;
    if (bid < 512) {
        int u = bid * 256 + tid;             // [i][o][lane2] lane2 = lane pair
        int lane2 = u & 31, o = (u >> 5) & 63, i = u >> 11;
        int l0 = lane2 * 2;
        f16x8 v;
        if (lane2 < 16) {                    // rows l0,l0+1; k=0..3 -> w[0..3]
#pragma unroll
            for (int t = 0; t < 2; ++t) {
                const float* w = W1 + (size_t)((i * 64 + o) * 32 + l0 + t) * 7;
#pragma unroll
                for (int j = 0; j < 4; ++j) v[t * 4 + j] = (f16)(w[j] * (-LOG2E));
            }
        } else {                             // rows l0-32,l0-31; k=4..7 -> w[4..6],B1
#pragma unroll
            for (int t = 0; t < 2; ++t) {
                int m = l0 - 32 + t;
                const float* w = W1 + (size_t)((i * 64 + o) * 32 + m) * 7;
                v[t * 4 + 0] = (f16)(w[4] * (-LOG2E));
                v[t * 4 + 1] = (f16)(w[5] * (-LOG2E));
                v[t * 4 + 2] = (f16)(w[6] * (-LOG2E));
                v[t * 4 + 3] = (f16)(B1[(i * 64 + o) * 32 + m] * (-LOG2E));
            }
        }
        *(f16x8*)(w1img + (size_t)u * 8) = v;
    } else if (bid < 1024) {
        int u = (bid - 512) * 256 + tid;     // [i][btp][lane2]
        int lane2 = u & 31, btp = (u >> 5) & 63, i = u >> 11;
        int l0 = lane2 * 2;
        f16x8 v;
#pragma unroll
        for (int t = 0; t < 2; ++t) {
            int b = btp * 32 + ((l0 + t) & 31);
            float xv = x[b * 64 + i];
            float s1, c1;
            __sincosf(xv, &s1, &c1);
            float s2 = 2.0f * s1 * c1, c2 = 1.0f - 2.0f * s1 * s1;
            float s4 = 2.0f * s2 * c2, c4 = 1.0f - 2.0f * s2 * s2;
            if (lane2 < 16) { v[t*4+0] = (f16)xv; v[t*4+1] = (f16)s1;
                              v[t*4+2] = (f16)s2; v[t*4+3] = (f16)s4; }
            else            { v[t*4+0] = (f16)c1; v[t*4+1] = (f16)c2;
                              v[t*4+2] = (f16)c4; v[t*4+3] = (f16)1.0f; }
        }
        *(f16x8*)(fimg + (size_t)u * 8) = v;
    } else if (bid < 1152) {
        int t = (bid - 1024) * 256 + tid;    // < 32768 float4s
        floatx4 v = *(const floatx4*)(W2 + (size_t)t * 4);
        v *= (-1.0f / LOG2E);
        *(floatx4*)(w2q + (size_t)t * 4) = v;
    } else if (bid < 1280) {
        int t = (bid - 1152) * 256 + tid;    // zero out[] (atomics accumulate)
        floatx4 z = {};
        *(floatx4*)(out + (size_t)t * 4) = z;
    } else if (tid < 64) {
        float s = 0.0f;
        for (int i = 0; i < 64; ++i) s += B2[i * 64 + tid];
        b2sum[tid] = s;
    }
}

// ---------------------------------------------------------------------------
// main: grid = 4 ig x 32 og x 64 btp = 8192 blocks, block = 128 (2 waves);
// wave w -> o = og*2+w, i in [ig*16, ig*16+16). Per i: ONE mfma_32x32x8
// (K=8 exact) -> C[h(32) x b(32)]. w2 slice staged in LDS (broadcast
// ds_read_b128). silu with 4-way batched reciprocals, VECTORIZED over the
// 4 r-groups as floatx4 ops so the backend emits v_pk_*_f32 (dual-issue
// packed f32): ~36 pk instrs replace ~70 scalar VALU per iter. Trans count
// unchanged (16 exp2 + 4 rcp / iter — the algorithmic floor).
// a/b image loads prefetched TWO iterations ahead (3 register sets) to
// cover L2 latency (~200-300 cy) now that per-iter issue is ~230 cy.
// Results atomically added to out, carrying 1/NIG of b2sum each.
// ---------------------------------------------------------------------------
__global__ __launch_bounds__(128, 4) void main_kernel(
        const f16* __restrict__ w1img, const f16* __restrict__ fimg,
        const float* __restrict__ w2q, const float* __restrict__ b2sum,
        float* __restrict__ out) {
    const int tid  = threadIdx.x;
    const int lane = tid & 63;
    const int wv   = tid >> 6;
    const int btp  = blockIdx.x & 63;
    const int og   = (blockIdx.x >> 6) & 31;
    const int ig   = blockIdx.x >> 11;
    const int o    = __builtin_amdgcn_readfirstlane(og * 2 + wv);
    const int p    = lane >> 5;
    const size_t ibase = (size_t)ig * IGW;

    // stage w2 slice: [wave][ii][h]; +1 pad row so tail reads stay in-bounds
    __shared__ float ws2[2][IGW + 1][32];
    {
        int idx = tid * 8;                         // 8 floats per thread
        int wv_ = idx >> 9, ii_ = (idx >> 5) & 15, h_ = idx & 31;
        const float* src = w2q + (ibase + ii_) * 2048
                         + (size_t)(og * 2 + wv_) * 32 + h_;
        *(floatx4*)&ws2[wv_][ii_][h_]     = *(const floatx4*)src;
        *(floatx4*)&ws2[wv_][ii_][h_ + 4] = *(const floatx4*)(src + 4);
    }
    __syncthreads();

    const f16* ap = w1img + ibase * 16384 + ((size_t)o   * 64 + lane) * 4;
    const f16* bp = fimg  + ibase * 16384 + ((size_t)btp * 64 + lane) * 4;

    // prefetch ii = 0, 1 (2-deep pipeline; tail prefetches overrun into the
    // adjacent ws regions — loaded but never consumed, always in-bounds)
    f16x4 a0 = *(const f16x4*)ap;
    f16x4 b0 = *(const f16x4*)bp;
    f16x4 a1 = *(const f16x4*)(ap + 16384);
    f16x4 b1 = *(const f16x4*)(bp + 16384);

    floatx4 phiv = {};
    const floatx16 zeroC = {};

#pragma unroll 1
    for (int ii = 0; ii < IGW; ++ii) {
        const f16x4 ca = a0, cb = b0;
        a0 = a1; b0 = b1;
        const size_t i2 = (size_t)(ii + 2);
        a1 = *(const f16x4*)(ap + i2 * 16384);
        b1 = *(const f16x4*)(bp + i2 * 16384);

        const float* wrow = &ws2[wv][ii][p * 4];
        const floatx4 CW0 = *(const floatx4*)(wrow);
        const floatx4 CW1 = *(const floatx4*)(wrow + 8);
        const floatx4 CW2 = *(const floatx4*)(wrow + 16);
        const floatx4 CW3 = *(const floatx4*)(wrow + 24);

        floatx16 C = __builtin_amdgcn_mfma_f32_32x32x8f16(ca, cb, zeroC, 0, 0, 0);

        // quad-vectors over r (independent lanes -> packed f32 math)
        floatx4 A0 = {C[0],  C[1],  C[2],  C[3]};
        floatx4 A1v = {C[4],  C[5],  C[6],  C[7]};
        floatx4 A2 = {C[8],  C[9],  C[10], C[11]};
        floatx4 A3 = {C[12], C[13], C[14], C[15]};

        floatx4 E0, E1, E2, E3;
#pragma unroll
        for (int j = 0; j < 4; ++j) {
            E0[j] = __builtin_amdgcn_exp2f(A0[j]);
            E1[j] = __builtin_amdgcn_exp2f(A1v[j]);
            E2[j] = __builtin_amdgcn_exp2f(A2[j]);
            E3[j] = __builtin_amdgcn_exp2f(A3[j]);
        }
        floatx4 D0 = E0 + 1.0f, D1 = E1 + 1.0f;
        floatx4 D2 = E2 + 1.0f, D3 = E3 + 1.0f;
        floatx4 U0 = A0 * CW0, U1 = A1v * CW1;
        floatx4 U2 = A2 * CW2, U3 = A3 * CW3;
        // 4-way batched reciprocal (per vector lane = one r-group):
        floatx4 N01 = U0 * D1 + U1 * D0;
        floatx4 N23 = U2 * D3 + U3 * D2;
        floatx4 P01 = D0 * D1, P23 = D2 * D3;
        floatx4 N   = N01 * P23 + N23 * P01;
        floatx4 DD  = P01 * P23;
        floatx4 R;
#pragma unroll
        for (int j = 0; j < 4; ++j) R[j] = __builtin_amdgcn_rcpf(DD[j]);
        phiv = phiv + N * R;
    }

    float phi = (phiv[0] + phiv[1]) + (phiv[2] + phiv[3]);
    // combine the two row-halves (lane and lane^32 share the same column)
    phi += __shfl_xor(phi, 32, 64);

    if (lane < 32) {
        float v = phi + 0.25f * b2sum[o];   // 1/NIG of bias per contribution
        unsafeAtomicAdd(out + (size_t)(btp * 32 + lane) * 64 + o, v);
    }
}

extern "C" void kernel_launch(void* const* d_in, const int* in_sizes, int n_in,
                              void* d_out, int out_size, void* d_ws, size_t ws_size,
                              hipStream_t stream) {
    const float* x  = (const float*)d_in[0];
    const float* W1 = (const float*)d_in[1];
    const float* W2 = (const float*)d_in[2];
    const float* B1 = (const float*)d_in[3];
    const float* B2 = (const float*)d_in[4];
    float* out = (float*)d_out;

    // ws: w1img (2MB) | fimg (2MB) | w2q (512KB) | b2sum | (overrun pad lives
    // in the contiguity of these regions; prefetch spills land in-bounds)
    f16*   w1img = (f16*)d_ws;
    f16*   fimg  = w1img + W1IMG_ELEMS;
    float* w2q   = (float*)(fimg + FIMG_ELEMS);
    float* b2sum = w2q + W2Q_ELEMS;

    prep_kernel<<<1281, 256, 0, stream>>>(W1, B1, W2, B2, x, w1img, fimg, w2q, b2sum, out);
    main_kernel<<<NIG * 32 * 64, 128, 0, stream>>>(w1img, fimg, w2q, b2sum, out);
}